// Round 6
// baseline (7157.336 us; speedup 1.0000x reference)
//
#include <hip/hip_runtime.h>
#include <math.h>
#include <stdint.h>

#define NN 500000
#define NE 16000000
#define NTL 245                   // dst tiles of 2048 (dst >> 11)
#define NG 62                     // src groups of 8192 (src >> 13)
#define NF4 125000                // NN/4
#define PB 65536                  // edges per partition block
#define NPB ((NE + PB - 1) / PB)  // 245
#define SLOT 67904                // fixed chunk slot: mean 65306, sigma~256, +10 sigma

// ---------------- phase 1: partition edges into fixed dst-tile slots ------
// word = (dst&2047)<<19 | src (19b). No prescan: chunk c owns
// ebuf[c*SLOT ...). 267-edge runs per bucket per block.
__global__ __launch_bounds__(1024) void partition_kernel(const int4* __restrict__ src4,
                                                         const int4* __restrict__ dst4,
                                                         int* __restrict__ bcnt,
                                                         uint32_t* __restrict__ ebuf) {
    __shared__ int lh[NTL];
    for (int i = threadIdx.x; i < NTL; i += 1024) lh[i] = 0;
    __syncthreads();
    long base4 = (long)blockIdx.x * (PB / 4);
    for (int k = 0; k < PB / 4; k += 1024) {
        long i4 = base4 + k + threadIdx.x;
        if (i4 < NE / 4) {
            int4 d = dst4[i4];
            atomicAdd(&lh[d.x >> 11], 1);
            atomicAdd(&lh[d.y >> 11], 1);
            atomicAdd(&lh[d.z >> 11], 1);
            atomicAdd(&lh[d.w >> 11], 1);
        }
    }
    __syncthreads();
    for (int i = threadIdx.x; i < NTL; i += 1024) {
        int c = lh[i];
        if (c) lh[i] = atomicAdd(&bcnt[i], c);   // reserve run; lh = block cursor
    }
    __syncthreads();
    for (int k = 0; k < PB / 4; k += 1024) {
        long i4 = base4 + k + threadIdx.x;
        if (i4 < NE / 4) {
            int4 d = dst4[i4];
            int4 s = src4[i4];
            int ch, rel;
            ch = d.x >> 11; rel = atomicAdd(&lh[ch], 1);
            if (rel < SLOT) ebuf[(size_t)ch * SLOT + rel] = ((uint32_t)(d.x & 2047) << 19) | (uint32_t)s.x;
            ch = d.y >> 11; rel = atomicAdd(&lh[ch], 1);
            if (rel < SLOT) ebuf[(size_t)ch * SLOT + rel] = ((uint32_t)(d.y & 2047) << 19) | (uint32_t)s.y;
            ch = d.z >> 11; rel = atomicAdd(&lh[ch], 1);
            if (rel < SLOT) ebuf[(size_t)ch * SLOT + rel] = ((uint32_t)(d.z & 2047) << 19) | (uint32_t)s.z;
            ch = d.w >> 11; rel = atomicAdd(&lh[ch], 1);
            if (rel < SLOT) ebuf[(size_t)ch * SLOT + rel] = ((uint32_t)(d.w & 2047) << 19) | (uint32_t)s.w;
        }
    }
}

// ---------------- phase 2: tiny serial scan of 245 chunk bases ------------
__global__ void cbase_scan(const int* __restrict__ bcnt, int* __restrict__ cbase) {
    if (threadIdx.x == 0) {
        int run = 0;
        for (int c = 0; c < NTL; c++) {
            cbase[c] = run;
            int n = bcnt[c];
            run += (n > SLOT) ? SLOT : n;
        }
        cbase[NTL] = run;
    }
}

// ---------------- phase 3: per-chunk sort by src-group + dis/z0 -----------
// Global 2-pass counting sort (chunk 260KB doesn't fit LDS): pass1 per-wave
// group hist + per-dst degree; pass2 scatter to sorted[] repacked as
// (dlo<<13)|(src&8191). Block owns tile exclusively -> dis/z0 plain writes.
__global__ __launch_bounds__(1024) void subsort_kernel(const int* __restrict__ bcnt,
                                                       const int* __restrict__ cbase,
                                                       const uint32_t* __restrict__ ebuf,
                                                       uint32_t* __restrict__ sorted,
                                                       int* __restrict__ sstart,
                                                       const float* __restrict__ x0,
                                                       float* __restrict__ dis,
                                                       float* __restrict__ z0) {
    __shared__ int whist[16][64];         // per-wave group hist (62 used)
    __shared__ int cur[NG + 1];
    __shared__ int dh[2048];              // per-dst degree counters
    int c = blockIdx.x;
    long abase = (long)c * SLOT;
    int n = bcnt[c];
    if (n > SLOT) n = SLOT;
    int obase = cbase[c];
    int wid = threadIdx.x >> 6;
    for (int i = threadIdx.x; i < 16 * 64; i += 1024) ((int*)whist)[i] = 0;
    for (int i = threadIdx.x; i < 2048; i += 1024) dh[i] = 0;
    __syncthreads();
    const uint4* eb4 = (const uint4*)(ebuf + abase);
    int n4 = n >> 2;
    for (int i4 = threadIdx.x; i4 < n4; i4 += 1024) {
        uint4 w = eb4[i4];
        atomicAdd(&whist[wid][(w.x & 0x7FFFFu) >> 13], 1); atomicAdd(&dh[w.x >> 19], 1);
        atomicAdd(&whist[wid][(w.y & 0x7FFFFu) >> 13], 1); atomicAdd(&dh[w.y >> 19], 1);
        atomicAdd(&whist[wid][(w.z & 0x7FFFFu) >> 13], 1); atomicAdd(&dh[w.z >> 19], 1);
        atomicAdd(&whist[wid][(w.w & 0x7FFFFu) >> 13], 1); atomicAdd(&dh[w.w >> 19], 1);
    }
    for (int i = (n4 << 2) + threadIdx.x; i < n; i += 1024) {
        uint32_t w = ebuf[abase + i];
        atomicAdd(&whist[wid][(w & 0x7FFFFu) >> 13], 1); atomicAdd(&dh[w >> 19], 1);
    }
    __syncthreads();
    if (threadIdx.x == 0) {               // 62-entry serial scan: trivial
        int run = 0;
        for (int g = 0; g < NG; g++) {
            int tot = 0;
            for (int q = 0; q < 16; q++) tot += whist[q][g];
            cur[g] = run;
            sstart[c * (NG + 1) + g] = obase + run;
            run += tot;
        }
        sstart[c * (NG + 1) + NG] = obase + run;   // == obase + n
    }
    // dis/z0 for owned tile (exclusive -> plain writes)
    for (int j = threadIdx.x; j < 2048; j += 1024) {
        int v = c * 2048 + j;
        if (v < NN) {
            float dv = rsqrtf((float)(dh[j] + 1));  // +1 self loop
            dis[v] = dv;
            z0[v] = x0[v] * dv;
        }
    }
    __syncthreads();
    for (int i4 = threadIdx.x; i4 < n4; i4 += 1024) {
        uint4 w = eb4[i4];
        int pos;
        pos = atomicAdd(&cur[(w.x & 0x7FFFFu) >> 13], 1);
        sorted[obase + pos] = ((w.x >> 19) << 13) | (w.x & 8191u);
        pos = atomicAdd(&cur[(w.y & 0x7FFFFu) >> 13], 1);
        sorted[obase + pos] = ((w.y >> 19) << 13) | (w.y & 8191u);
        pos = atomicAdd(&cur[(w.z & 0x7FFFFu) >> 13], 1);
        sorted[obase + pos] = ((w.z >> 19) << 13) | (w.z & 8191u);
        pos = atomicAdd(&cur[(w.w & 0x7FFFFu) >> 13], 1);
        sorted[obase + pos] = ((w.w >> 19) << 13) | (w.w & 8191u);
    }
    for (int i = (n4 << 2) + threadIdx.x; i < n; i += 1024) {
        uint32_t w = ebuf[abase + i];
        int pos = atomicAdd(&cur[(w & 0x7FFFFu) >> 13], 1);
        sorted[obase + pos] = ((w >> 19) << 13) | (w & 8191u);
    }
}

// ---------------- per-layer: fused scatter + epilogue (ONE kernel) --------
// Block = dst-tile of 2048. Loop over 62 src-groups: reg-prefetch next
// ztile (T14 split: issue loads during edge phase, LDS-store after barrier)
// while current group's edges run entirely in LDS. Epilogue applies
// dis/comb/act from complete sums -> no partials, no combine kernel, and
// the per-layer dirty set is just z (2MB) instead of hp (16MB).
__global__ __launch_bounds__(1024) void layer_kernel(const int* __restrict__ sstart,
                                                     const uint32_t* __restrict__ eb,
                                                     const float* __restrict__ zin,
                                                     const float* __restrict__ dis,
                                                     const float* __restrict__ x0,
                                                     const float* __restrict__ w,
                                                     int li, int act,
                                                     float* __restrict__ zout,
                                                     int* __restrict__ out) {
    __shared__ float acc[2048];
    __shared__ float ztile[8192];
    int c = blockIdx.x;
    int tid = threadIdx.x;
    acc[tid] = 0.f;
    acc[tid + 1024] = 0.f;
    const float4* zin4 = (const float4*)zin;
    float4* zt4 = (float4*)ztile;
    int nf = 2048;                        // float4 count of group 0
    float4 r0 = zin4[tid];
    float4 r1 = zin4[1024 + tid];
    int e_lo = sstart[c * (NG + 1)];
    for (int g = 0; g < NG; g++) {
        int e_hi = sstart[c * (NG + 1) + g + 1];
        __syncthreads();                  // prev group's ztile readers done (g=0: acc init)
        if (tid < nf) zt4[tid] = r0;
        if (1024 + tid < nf) zt4[1024 + tid] = r1;
        int nn = 0;
        if (g + 1 < NG) {                 // issue next group's loads early
            int fb = (g + 1) << 11;
            nn = NF4 - fb; if (nn > 2048) nn = 2048;
            if (tid < nn) r0 = zin4[fb + tid];
            if (1024 + tid < nn) r1 = zin4[fb + 1024 + tid];
        }
        __syncthreads();                  // ztile visible
        for (int i = e_lo + tid; i < e_hi; i += 1024) {
            uint32_t e = eb[i];
            atomicAdd(&acc[e >> 13], ztile[e & 8191u]);
        }
        e_lo = e_hi;
        nf = nn;
    }
    __syncthreads();
    float wl = w[li];
    for (int j = tid; j < 2048; j += 1024) {
        int v = c * 2048 + j;
        if (v >= NN) break;
        float s = acc[j] + zin[v];                      // self loop
        float y = (0.7f * dis[v] * s + 0.3f * x0[v]) * wl;
        if (act == 4) {
            out[v] = (int)(500000.f / (1.f + expf(-y)));
        } else {
            float r;
            if (act == 0)      r = y;
            else if (act == 1) r = fmaxf(y, 0.f);
            else if (act == 2) r = (y > 0.f) ? y : 0.01f * y;
            else               r = 1.f / (1.f + expf(-y));
            zout[v] = dis[v] * r;
        }
    }
}

// ---------------- launch ----------------
extern "C" void kernel_launch(void* const* d_in, const int* in_sizes, int n_in,
                              void* d_out, int out_size, void* d_ws, size_t ws_size,
                              hipStream_t stream) {
    const float* x0  = (const float*)d_in[0];
    const float* w   = (const float*)d_in[1];
    const int*   adj = (const int*)d_in[2];             // int32 (jax demotes int64)
    const int*   src = adj;
    const int*   dst = adj + NE;
    int* out = (int*)d_out;

    uintptr_t p = (uintptr_t)d_ws;
    auto alloc = [&](size_t bytes) -> void* {
        p = (p + 255) & ~(uintptr_t)255;
        void* r = (void*)p;
        p += bytes;
        return r;
    };
    float* dis    = (float*)alloc((size_t)NN * 4);
    float* z0     = (float*)alloc((size_t)NN * 4);
    float* z1     = (float*)alloc((size_t)NN * 4);
    int*   bcnt   = (int*)alloc((size_t)NTL * 4);
    int*   cbase  = (int*)alloc((size_t)(NTL + 1) * 4);
    int*   sstart = (int*)alloc((size_t)NTL * (NG + 1) * 4);
    uint32_t* slots  = (uint32_t*)alloc((size_t)NTL * SLOT * 4);  // 66.5MB
    uint32_t* sorted = (uint32_t*)alloc((size_t)NE * 4);          // 64MB
    (void)ws_size;

    hipMemsetAsync(bcnt, 0, (size_t)NTL * 4, stream);

    partition_kernel<<<NPB, 1024, 0, stream>>>((const int4*)src, (const int4*)dst, bcnt, slots);
    cbase_scan<<<1, 64, 0, stream>>>(bcnt, cbase);
    subsort_kernel<<<NTL, 1024, 0, stream>>>(bcnt, cbase, slots, sorted, sstart, x0, dis, z0);

    float* zbuf[2] = {z0, z1};
    for (int i = 0; i < 49; i++) {
        int act;
        if (i == 0)            act = 0;
        else if (i == 48)      act = 4;
        else if (i % 10 == 1)  act = 2;                 // leaky {1,11,21,31,41}
        else if (i % 10 == 4)  act = 3;                 // sigmoid {4,14,24,34,44}
        else                   act = 1;                 // relu
        layer_kernel<<<NTL, 1024, 0, stream>>>(sstart, sorted, zbuf[i & 1], dis, x0, w,
                                               i, act, zbuf[(i + 1) & 1], out);
    }
}

// Round 7
// 5237.114 us; speedup vs baseline: 1.3667x; 1.3667x over previous
//
#include <hip/hip_runtime.h>
#include <math.h>
#include <stdint.h>

#define NN 500000
#define NE 16000000
#define NTILE 31                  // dst tiles of 16384 (dst >> 14)
#define DSZ 16384
#define NQ 8                      // src octants of 62500
#define OCTW 62500
#define NCH 248                   // 31 * 8
#define PB 65536                  // edges per partition block
#define NPB ((NE + PB - 1) / PB)  // 245
#define SLOT 68096                // mean 65536, sigma~255, +10 sigma, mult of 16
#define HPST 507904               // NTILE*DSZ (>= NN)
#define HP4 (HPST / 4)

// ---------------- phase 1: partition edges into 248 fixed chunk slots -----
// chunk = (dst>>14)*8 + src/62500. word = (dst&16383)<<16 | (src - q*62500).
// 264-edge runs per chunk per block -> ~full-line writes (r6-proven, 1.3x amp).
__global__ __launch_bounds__(1024) void partition_kernel(const int4* __restrict__ src4,
                                                         const int4* __restrict__ dst4,
                                                         int* __restrict__ bcnt,
                                                         uint32_t* __restrict__ ebuf) {
    __shared__ int lh[NCH];
    for (int i = threadIdx.x; i < NCH; i += 1024) lh[i] = 0;
    __syncthreads();
    long base4 = (long)blockIdx.x * (PB / 4);
    for (int k = 0; k < PB / 4; k += 1024) {
        long i4 = base4 + k + threadIdx.x;
        if (i4 < NE / 4) {
            int4 d = dst4[i4];
            int4 s = src4[i4];
            atomicAdd(&lh[((d.x >> 14) << 3) + s.x / OCTW], 1);
            atomicAdd(&lh[((d.y >> 14) << 3) + s.y / OCTW], 1);
            atomicAdd(&lh[((d.z >> 14) << 3) + s.z / OCTW], 1);
            atomicAdd(&lh[((d.w >> 14) << 3) + s.w / OCTW], 1);
        }
    }
    __syncthreads();
    for (int i = threadIdx.x; i < NCH; i += 1024) {
        int c = lh[i];
        if (c) lh[i] = atomicAdd(&bcnt[i], c);   // reserve run; lh = block cursor
    }
    __syncthreads();
    for (int k = 0; k < PB / 4; k += 1024) {
        long i4 = base4 + k + threadIdx.x;
        if (i4 < NE / 4) {
            int4 d = dst4[i4];
            int4 s = src4[i4];
            int q, ch, rel;
            q = s.x / OCTW; ch = ((d.x >> 14) << 3) + q; rel = atomicAdd(&lh[ch], 1);
            if (rel < SLOT) ebuf[(size_t)ch * SLOT + rel] =
                ((uint32_t)(d.x & 16383) << 16) | (uint32_t)(s.x - q * OCTW);
            q = s.y / OCTW; ch = ((d.y >> 14) << 3) + q; rel = atomicAdd(&lh[ch], 1);
            if (rel < SLOT) ebuf[(size_t)ch * SLOT + rel] =
                ((uint32_t)(d.y & 16383) << 16) | (uint32_t)(s.y - q * OCTW);
            q = s.z / OCTW; ch = ((d.z >> 14) << 3) + q; rel = atomicAdd(&lh[ch], 1);
            if (rel < SLOT) ebuf[(size_t)ch * SLOT + rel] =
                ((uint32_t)(d.z & 16383) << 16) | (uint32_t)(s.z - q * OCTW);
            q = s.w / OCTW; ch = ((d.w >> 14) << 3) + q; rel = atomicAdd(&lh[ch], 1);
            if (rel < SLOT) ebuf[(size_t)ch * SLOT + rel] =
                ((uint32_t)(d.w & 16383) << 16) | (uint32_t)(s.w - q * OCTW);
        }
    }
}

// ---------------- phase 2: tiny serial scan of 248 chunk bases ------------
__global__ void cbase_scan(const int* __restrict__ bcnt, int* __restrict__ cbase) {
    if (threadIdx.x == 0) {
        int run = 0;
        for (int c = 0; c < NCH; c++) {
            cbase[c] = run;
            int n = bcnt[c];
            run += (n > SLOT) ? SLOT : n;
        }
        cbase[NCH] = run;
    }
}

// ---------------- phase 3: per-chunk 8-bucket sort (by src subchunk) ------
// Pass1: per-wave bucket hist + per-dst degree (LDS). Per-wave cursor ranges
// -> pass2 writes are 8 SEQUENTIAL streams per wave (no partial-line scatter).
// Bucket b = slo>>13 (src subchunk of 8192 within octant).
__global__ __launch_bounds__(1024) void subsort_kernel(const int* __restrict__ bcnt,
                                                       const int* __restrict__ cbase,
                                                       const uint32_t* __restrict__ ebuf,
                                                       uint32_t* __restrict__ sorted,
                                                       int* __restrict__ sstart,
                                                       int* __restrict__ deg) {
    __shared__ int dh[DSZ];               // 64KB per-dst degree
    __shared__ int whist[16][8];
    __shared__ int wcur[16][8];
    __shared__ int bb[9];
    int c = blockIdx.x;
    long abase = (long)c * SLOT;
    int n = bcnt[c];
    if (n > SLOT) n = SLOT;
    int obase = cbase[c];
    int t = c >> 3;
    int wid = threadIdx.x >> 6;
    for (int i = threadIdx.x; i < DSZ; i += 1024) dh[i] = 0;
    if (threadIdx.x < 128) ((int*)whist)[threadIdx.x] = 0;
    __syncthreads();
    const uint4* eb4 = (const uint4*)(ebuf + abase);
    int n4 = n >> 2;
    for (int i = threadIdx.x; i < n4; i += 1024) {
        uint4 w = eb4[i];
        atomicAdd(&whist[wid][(w.x & 0xFFFFu) >> 13], 1); atomicAdd(&dh[w.x >> 16], 1);
        atomicAdd(&whist[wid][(w.y & 0xFFFFu) >> 13], 1); atomicAdd(&dh[w.y >> 16], 1);
        atomicAdd(&whist[wid][(w.z & 0xFFFFu) >> 13], 1); atomicAdd(&dh[w.z >> 16], 1);
        atomicAdd(&whist[wid][(w.w & 0xFFFFu) >> 13], 1); atomicAdd(&dh[w.w >> 16], 1);
    }
    for (int i = (n4 << 2) + threadIdx.x; i < n; i += 1024) {
        uint32_t w = ebuf[abase + i];
        atomicAdd(&whist[wid][(w & 0xFFFFu) >> 13], 1); atomicAdd(&dh[w >> 16], 1);
    }
    __syncthreads();
    if (threadIdx.x == 0) {               // 8-bucket serial scan: trivial
        int run = 0;
        for (int b = 0; b < 8; b++) {
            bb[b] = run;
            sstart[c * 9 + b] = obase + run;
            int tot = 0;
            for (int w2 = 0; w2 < 16; w2++) tot += whist[w2][b];
            run += tot;
        }
        sstart[c * 9 + 8] = obase + run;  // == obase + n
    }
    __syncthreads();
    if (threadIdx.x < 8) {                // per-wave start cursors
        int b = threadIdx.x;
        int run = obase + bb[b];
        for (int w2 = 0; w2 < 16; w2++) { wcur[w2][b] = run; run += whist[w2][b]; }
    }
    for (int i = threadIdx.x; i < DSZ; i += 1024) {   // degree -> global
        int d = dh[i];
        if (d) atomicAdd(&deg[t * DSZ + i], d);
    }
    __syncthreads();
    // pass 2: identical iteration pattern -> wave matches its reserved ranges
    for (int i = threadIdx.x; i < n4; i += 1024) {
        uint4 w = eb4[i];
        int pos;
        pos = atomicAdd(&wcur[wid][(w.x & 0xFFFFu) >> 13], 1); sorted[pos] = w.x;
        pos = atomicAdd(&wcur[wid][(w.y & 0xFFFFu) >> 13], 1); sorted[pos] = w.y;
        pos = atomicAdd(&wcur[wid][(w.z & 0xFFFFu) >> 13], 1); sorted[pos] = w.z;
        pos = atomicAdd(&wcur[wid][(w.w & 0xFFFFu) >> 13], 1); sorted[pos] = w.w;
    }
    for (int i = (n4 << 2) + threadIdx.x; i < n; i += 1024) {
        uint32_t w = ebuf[abase + i];
        int pos = atomicAdd(&wcur[wid][(w & 0xFFFFu) >> 13], 1); sorted[pos] = w;
    }
}

__global__ void dis_kernel(const int* __restrict__ deg, const float* __restrict__ x0,
                           float* __restrict__ dis, float* __restrict__ z0) {
    int v = blockIdx.x * 1024 + threadIdx.x;
    if (v < NN) {
        float d = rsqrtf((float)(deg[v] + 1));   // +1 self loop
        dis[v] = d;
        z0[v] = x0[v] * d;
    }
}

// ---------------- per-layer A: big-tile LDS scatter -----------------------
// Block = chunk (t of 16384 dst, q of 62500 src). Loop 8 src-subchunks:
// reg-prefetch next ztile (issued before edge phase, stored after barrier ->
// HBM/L3 latency hides under ~8 LDS-atomics/thread), edges entirely in LDS.
// Staging total/layer = 31 tiles x 2MB = 62MB (vs 490MB in the r6 design).
// LDS 96KB -> 1 block/CU.
__global__ __launch_bounds__(1024) void scatter_kernel(const int* __restrict__ sstart,
                                                       const uint32_t* __restrict__ eb,
                                                       const float* __restrict__ zin,
                                                       float* __restrict__ hp) {
    __shared__ float acc[DSZ];            // 64KB
    __shared__ float zt[8192];            // 32KB
    int c = blockIdx.x;
    int tid = threadIdx.x;
    int t = c >> 3, q = c & 7;
    for (int i = tid; i < DSZ; i += 1024) acc[i] = 0.f;
    const float4* zin4 = (const float4*)zin;
    float4* zt4 = (float4*)zt;
    int ob4 = (q * OCTW) >> 2;            // octant float4 base (62500%4==0)
    float4 r0 = zin4[ob4 + tid];          // k=0 prefetch (cnt4=2048: both valid)
    float4 r1 = zin4[ob4 + 1024 + tid];
    int base9 = c * 9;
    int lo = sstart[base9];
    for (int k = 0; k < 8; k++) {
        int hi = sstart[base9 + k + 1];
        int cnt4 = min(2048, 15625 - (k << 11));
        __syncthreads();                  // prev subchunk's zt readers done
        if (tid < cnt4) zt4[tid] = r0;
        if (1024 + tid < cnt4) zt4[1024 + tid] = r1;
        if (k < 7) {                      // issue next subchunk's loads early
            int nb4 = ob4 + ((k + 1) << 11);
            int nc4 = min(2048, 15625 - ((k + 1) << 11));
            if (tid < nc4) r0 = zin4[nb4 + tid];
            if (1024 + tid < nc4) r1 = zin4[nb4 + 1024 + tid];
        }
        __syncthreads();                  // zt visible
        int koff = k << 13;
        for (int i = lo + tid; i < hi; i += 1024) {
            uint32_t w = eb[i];
            atomicAdd(&acc[w >> 16], zt[(int)(w & 0xFFFFu) - koff]);
        }
        lo = hi;
    }
    __syncthreads();
    float4* dst4 = (float4*)(hp + (size_t)q * HPST + (size_t)t * DSZ);
    const float4* a4 = (const float4*)acc;
    for (int i = tid; i < DSZ / 4; i += 1024) dst4[i] = a4[i];
}

// ---------------- per-layer B: combine 8 partials + activation (float4) ---
__global__ __launch_bounds__(512) void combine_kernel(const float4* __restrict__ hp4,
        const float4* __restrict__ zin4, const float4* __restrict__ dis4,
        const float4* __restrict__ x04, const float* __restrict__ w,
        int li, int act, float4* __restrict__ zout4, int4* __restrict__ out4) {
    int v4 = blockIdx.x * 512 + threadIdx.x;            // NN/4 = 125000 units
    if (v4 >= NN / 4) return;
    float4 s = zin4[v4];                                // self loop
    #pragma unroll
    for (int q = 0; q < NQ; q++) {
        float4 hq = hp4[(size_t)q * HP4 + v4];
        s.x += hq.x; s.y += hq.y; s.z += hq.z; s.w += hq.w;
    }
    float4 dv = dis4[v4];
    float4 xv = x04[v4];
    float wl = w[li];
    float y0 = (0.7f * dv.x * s.x + 0.3f * xv.x) * wl;
    float y1 = (0.7f * dv.y * s.y + 0.3f * xv.y) * wl;
    float y2 = (0.7f * dv.z * s.z + 0.3f * xv.z) * wl;
    float y3 = (0.7f * dv.w * s.w + 0.3f * xv.w) * wl;
    if (act == 4) {
        int4 o;
        o.x = (int)(500000.f / (1.f + expf(-y0)));
        o.y = (int)(500000.f / (1.f + expf(-y1)));
        o.z = (int)(500000.f / (1.f + expf(-y2)));
        o.w = (int)(500000.f / (1.f + expf(-y3)));
        out4[v4] = o;
        return;
    }
    float r0, r1, r2, r3;
    if (act == 0)      { r0 = y0; r1 = y1; r2 = y2; r3 = y3; }
    else if (act == 1) { r0 = fmaxf(y0, 0.f); r1 = fmaxf(y1, 0.f);
                         r2 = fmaxf(y2, 0.f); r3 = fmaxf(y3, 0.f); }
    else if (act == 2) { r0 = (y0 > 0.f) ? y0 : 0.01f * y0;
                         r1 = (y1 > 0.f) ? y1 : 0.01f * y1;
                         r2 = (y2 > 0.f) ? y2 : 0.01f * y2;
                         r3 = (y3 > 0.f) ? y3 : 0.01f * y3; }
    else               { r0 = 1.f / (1.f + expf(-y0)); r1 = 1.f / (1.f + expf(-y1));
                         r2 = 1.f / (1.f + expf(-y2)); r3 = 1.f / (1.f + expf(-y3)); }
    float4 zo;
    zo.x = dv.x * r0; zo.y = dv.y * r1; zo.z = dv.z * r2; zo.w = dv.w * r3;
    zout4[v4] = zo;
}

// ---------------- launch ----------------
extern "C" void kernel_launch(void* const* d_in, const int* in_sizes, int n_in,
                              void* d_out, int out_size, void* d_ws, size_t ws_size,
                              hipStream_t stream) {
    const float* x0  = (const float*)d_in[0];
    const float* w   = (const float*)d_in[1];
    const int*   adj = (const int*)d_in[2];             // int32 (jax demotes int64)
    const int*   src = adj;
    const int*   dst = adj + NE;
    int* out = (int*)d_out;

    uintptr_t p = (uintptr_t)d_ws;
    auto alloc = [&](size_t bytes) -> void* {
        p = (p + 255) & ~(uintptr_t)255;
        void* r = (void*)p;
        p += bytes;
        return r;
    };
    float* dis    = (float*)alloc((size_t)NN * 4);
    float* z0     = (float*)alloc((size_t)NN * 4);
    float* z1     = (float*)alloc((size_t)NN * 4);
    int*   deg    = (int*)alloc((size_t)NTILE * DSZ * 4);         // 2MB
    int*   bcnt   = (int*)alloc((size_t)NCH * 4);
    int*   cbase  = (int*)alloc((size_t)(NCH + 1) * 4);
    int*   sstart = (int*)alloc((size_t)NCH * 9 * 4);
    uint32_t* slots  = (uint32_t*)alloc((size_t)NCH * SLOT * 4);  // 67.5MB
    uint32_t* sorted = (uint32_t*)alloc((size_t)NE * 4);          // 64MB
    float* hp     = (float*)alloc((size_t)NQ * HPST * 4);         // 16.25MB
    (void)ws_size;

    hipMemsetAsync(bcnt, 0, (size_t)NCH * 4, stream);
    hipMemsetAsync(deg, 0, (size_t)NTILE * DSZ * 4, stream);

    partition_kernel<<<NPB, 1024, 0, stream>>>((const int4*)src, (const int4*)dst, bcnt, slots);
    cbase_scan<<<1, 64, 0, stream>>>(bcnt, cbase);
    subsort_kernel<<<NCH, 1024, 0, stream>>>(bcnt, cbase, slots, sorted, sstart, deg);
    dis_kernel<<<(NN + 1023) / 1024, 1024, 0, stream>>>(deg, x0, dis, z0);

    float* zbuf[2] = {z0, z1};
    const int CB = (NN / 4 + 511) / 512;                // 245
    for (int i = 0; i < 49; i++) {
        int act;
        if (i == 0)            act = 0;
        else if (i == 48)      act = 4;
        else if (i % 10 == 1)  act = 2;                 // leaky {1,11,21,31,41}
        else if (i % 10 == 4)  act = 3;                 // sigmoid {4,14,24,34,44}
        else                   act = 1;                 // relu
        scatter_kernel<<<NCH, 1024, 0, stream>>>(sstart, sorted, zbuf[i & 1], hp);
        combine_kernel<<<CB, 512, 0, stream>>>((const float4*)hp, (const float4*)zbuf[i & 1],
                                               (const float4*)dis, (const float4*)x0, w,
                                               i, act, (float4*)zbuf[(i + 1) & 1], (int4*)out);
    }
}